// Round 12
// baseline (405.407 us; speedup 1.0000x reference)
//
#include <hip/hip_runtime.h>
#include <hip/hip_bf16.h>
#include <math.h>

// ---------------- constants ----------------
#define BATCH   16
#define TFRM    4096          // frames per batch (= L)
#define DIM     512
#define NFFT    1024
#define HOP     256
#define PADC    384           // (WIN-HOP)/2
#define MROWS   (BATCH*TFRM)  // 65536
#define OUTLEN  1048576       // per-batch output samples
#define TWO_PI_OVER_N 0.006135923151542565f  // 2*pi/1024
#define INV_TWO_PI    0.15915494309189535f   // 1/(2*pi)

typedef __bf16 bf16x8 __attribute__((ext_vector_type(8)));
typedef float  f32x4  __attribute__((ext_vector_type(4)));

__device__ __forceinline__ ushort f2bf(float f) {
  union { float f; unsigned u; } v; v.f = f;
  unsigned u = v.u;
  unsigned r = (u + 0x7FFFu + ((u >> 16) & 1u)) >> 16;
  return (ushort)r;
}
__device__ __forceinline__ float bf2f(ushort h) {
  union { unsigned u; float f; } v; v.u = ((unsigned)h) << 16;
  return v.f;
}
// HW transcendentals (single VALU op each; v_sin/v_cos take revolutions).
__device__ __forceinline__ float fast_sin(float x) { return __builtin_amdgcn_sinf(x * INV_TWO_PI); }
__device__ __forceinline__ float fast_cos(float x) { return __builtin_amdgcn_cosf(x * INV_TWO_PI); }
__device__ __forceinline__ float fast_exp(float x) { return __builtin_amdgcn_exp2f(x * 1.4426950408889634f); }
// lane-xor-1 exchange as a single VALU DPP op (quad_perm [1,0,3,2] = 0xB1).
__device__ __forceinline__ float dpp_xor1(float v) {
  return __int_as_float(__builtin_amdgcn_update_dpp(
      __float_as_int(v), __float_as_int(v), 0xB1, 0xF, 0xF, false));
}

// ---------------- prep: x fp32 -> bf16, fused Nyquist GEMV ----------------
__global__ void k_prep_x(const float* __restrict__ x, const float* __restrict__ W,
                         const float* __restrict__ bias,
                         ushort* __restrict__ xbf, float* __restrict__ s512) {
  const int row  = blockIdx.x * 4 + (threadIdx.x >> 6);
  const int lane = threadIdx.x & 63;
  const float* xr = x + (size_t)row * DIM + lane * 8;
  float4 v0 = *(const float4*)xr;
  float4 v1 = *(const float4*)(xr + 4);
  ushort4 u0, u1;
  u0.x = f2bf(v0.x); u0.y = f2bf(v0.y); u0.z = f2bf(v0.z); u0.w = f2bf(v0.w);
  u1.x = f2bf(v1.x); u1.y = f2bf(v1.y); u1.z = f2bf(v1.z); u1.w = f2bf(v1.w);
  ushort* xo = xbf + (size_t)row * DIM + lane * 8;
  *(ushort4*)xo = u0;
  *(ushort4*)(xo + 4) = u1;
  const float* w0 = W + 512 * DIM + lane * 8;    // mag row k=512
  const float* w1 = W + 1025 * DIM + lane * 8;   // phase row k=512
  float4 a0 = *(const float4*)w0, a1 = *(const float4*)(w0 + 4);
  float4 b0 = *(const float4*)w1, b1 = *(const float4*)(w1 + 4);
  float sm = v0.x*a0.x + v0.y*a0.y + v0.z*a0.z + v0.w*a0.w
           + v1.x*a1.x + v1.y*a1.y + v1.z*a1.z + v1.w*a1.w;
  float sp = v0.x*b0.x + v0.y*b0.y + v0.z*b0.z + v0.w*b0.w
           + v1.x*b1.x + v1.y*b1.y + v1.z*b1.z + v1.w*b1.w;
#pragma unroll
  for (int off = 32; off; off >>= 1) {
    sm += __shfl_down(sm, off);
    sp += __shfl_down(sp, off);
  }
  if (lane == 0) {
    float mag = fminf(fast_exp(sm + bias[512]), 100.0f);
    s512[row] = mag * fast_cos(sp + bias[1025]) * (1.0f / 1024.0f);
  }
}

// ---------------- prep: W fp32 -> bf16 interleaved [1024][512] ----------------
__global__ void k_prep_w(const float* __restrict__ W, ushort* __restrict__ o) {
  int i = blockIdx.x * 256 + threadIdx.x;          // over 1024*512
  int r = i >> 9;
  int c = i & 511;
  int orig = (r >> 1) + (r & 1) * 513;
  o[i] = f2bf(W[orig * DIM + c]);
}

// ---------------- basis: BasE/BasO [512 rows][512 K] bf16, row r -> n=r+1 ----------------
__global__ void k_basis(ushort* __restrict__ basE, ushort* __restrict__ basO) {
  int r = blockIdx.x;                              // 0..511
  int n = r + 1;
  for (int k = threadIdx.x; k < 512; k += 256) {
    float e, o;
    if (k == 0) { e = 1.0f / 1024.0f; o = 0.0f; }
    else {
      int ph = (k * n) & 1023;                     // exact integer phase reduction
      float ang = (float)ph * TWO_PI_OVER_N;
      e = 2.0f * cosf(ang) * (1.0f / 1024.0f);
      o = 2.0f * sinf(ang) * (1.0f / 1024.0f);
    }
    basE[r * 512 + k] = f2bf(e);
    basO[r * 512 + k] = f2bf(o);
  }
}

// ---------------- GEMM: C[m][n] = sum_k A[m][k]*Bt[n][k]  (bf16 in, fp32 acc)
// 128x128 tile, BK=32, 4 waves (2x2 of 64x64). KEY CHANGE vs round 11: B operands
// (basis/Wp — small, L2-resident, shared by every block) are loaded DIRECTLY
// global->VGPR in MFMA fragment order (per-lane dwordx4), double-buffered bE/bO
// with 2-tile prefetch issued AFTER the consuming MFMA cluster. LDS stages only A
// (ring-3 x 8 KB). This halves LDS read traffic per MFMA — the measured plateau:
// 32KB ds_read per 16KB staged per tile @ ~85 B/cyc capped MfmaUtil at ~21-23%
// across every schedule tried; A-only staging lifts the cap to ~42%.
// vmcnt audit (6 ops/iter: 2 A-stage + 4 B-load): end-of-iter vmcnt(6) lands
// A(t+1)+B(t+1); prologue order pinned by a compile-time fence; tail 0/none.
// Granule-XOR swizzle on A ((row>>1)&3) keeps LDS conflict-free. XCD-chunked grid.
// nsplit>0: blocks with bid>=nsplit run the (A2,Bt2,C2) problem.
// EPI=1: activation epilogue (LDS-staged, DPP mag/phase pairing), a_k->C, b_k->C2.
// EPI=0: E/O store unshifted; first problem folds (-1)^(i+1)*s512[row].
template<int EPI>
__global__ __launch_bounds__(256) void k_gemm(const ushort* A, const ushort* A2, int lda,
                                              const ushort* Bt, const ushort* Bt2, int ldb,
                                              ushort* C, ushort* C2, int ldc,
                                              int nbn, int NK, int nsplit,
                                              const float* __restrict__ bias,
                                              const float* __restrict__ s512) {
  __shared__ __align__(16) ushort lds[20480];  // 40 KB: ring-3 A slots (24K) / epilogue (40K)
  const int tid  = threadIdx.x;
  const int cpx  = gridDim.x >> 3;
  int bid  = (blockIdx.x & 7) * cpx + (blockIdx.x >> 3);   // XCD-chunked
  bool second = false;
  if (nsplit > 0 && bid >= nsplit) { second = true; A = A2; Bt = Bt2; C = C2; bid -= nsplit; }
  const int bm   = bid / nbn;
  const int bn   = bid - bm * nbn;
  const int lane = tid & 63;
  const int wv   = tid >> 6;
  const int wr   = (wv >> 1) * 64;
  const int wc   = (wv & 1) * 64;
  const int lr   = lane & 15;
  const int gx   = ((lane >> 4) ^ ((lane >> 1) & 3)) << 3; // swizzled A read granule

  f32x4 acc[4][4] = {};

  const int swz = ((tid & 3) ^ ((tid >> 3) & 3)) << 3;     // inverse-swizzled A source granule
  const ushort* gA = A + (size_t)(bm * 128 + (tid >> 2)) * lda + swz;
  auto stageA = [&](int t, int slot) {                     // 2 vmcnt ops
    const ushort* g0 = gA + t * 32;
    ushort* l = &lds[slot * 4096] + ((tid >> 6) << 9);
    __builtin_amdgcn_global_load_lds(
        (const __attribute__((address_space(1))) void*)g0,
        (__attribute__((address_space(3))) void*)l, 16, 0, 0);
    __builtin_amdgcn_global_load_lds(
        (const __attribute__((address_space(1))) void*)(g0 + (size_t)64 * lda),
        (__attribute__((address_space(3))) void*)(l + 2048), 16, 0, 0);
  };

  // B fragment base: row (bn*128 + wc + n*16 + lr), 8 bf16 at col t*32 + gq*8.
  const ushort* gB = Bt + (size_t)(bn * 128 + wc + lr) * ldb + ((lane >> 4) << 3);
  auto loadB = [&](int t, bf16x8* bf) {                    // 4 vmcnt ops
#pragma unroll
    for (int n = 0; n < 4; ++n)
      bf[n] = *(const bf16x8*)(gB + (size_t)(n * 16) * ldb + t * 32);
  };

  bf16x8 bE[4], bO[4];   // even-/odd-tile B fragment buffers (static names, rule #20)

  // prologue: FIFO must be [A0,B0 | A1,B1] so vmcnt(6) lands tile 0 — fence pins order.
  stageA(0, 0); loadB(0, bE);
  asm volatile("" ::: "memory");
  stageA(1, 1); loadB(1, bO);
  asm volatile("s_waitcnt vmcnt(6)" ::: "memory");
  __syncthreads();

  int sl = 0;                                              // slot of even tile t
  for (int t = 0; t < NK; t += 2) {
    const int s0 = sl;
    const int s1 = (s0 >= 2) ? s0 - 2 : s0 + 1;            // (s0+1)%3
#pragma unroll
    for (int h = 0; h < 2; ++h) {
      const int u = t + h;
      const int su = h ? s1 : s0;
      const int sp = h ? s0 : ((s0 >= 1) ? s0 - 1 : 2);    // (su+2)%3
      const ushort* lA = &lds[su * 4096];
      bf16x8 aF[4];
#pragma unroll
      for (int m = 0; m < 4; ++m)
        aF[m] = *(const bf16x8*)(lA + (wr + m * 16 + lr) * 32 + gx);
      if (u + 2 < NK) stageA(u + 2, sp);
      if (h == 0) {
#pragma unroll
        for (int m = 0; m < 4; ++m)
#pragma unroll
          for (int n = 0; n < 4; ++n)
            acc[m][n] = __builtin_amdgcn_mfma_f32_16x16x32_bf16(aF[m], bE[n], acc[m][n], 0, 0, 0);
        if (u + 2 < NK) loadB(u + 2, bE);  // after MFMA: no WAR on bE
      } else {
#pragma unroll
        for (int m = 0; m < 4; ++m)
#pragma unroll
          for (int n = 0; n < 4; ++n)
            acc[m][n] = __builtin_amdgcn_mfma_f32_16x16x32_bf16(aF[m], bO[n], acc[m][n], 0, 0, 0);
        if (u + 2 < NK) loadB(u + 2, bO);
      }
      if (u + 2 < NK)      asm volatile("s_waitcnt vmcnt(6)" ::: "memory");
      else if (u + 1 < NK) asm volatile("s_waitcnt vmcnt(0)" ::: "memory");
      if (u + 1 < NK) __syncthreads();
    }
    sl = (s1 >= 2) ? s1 - 2 : s1 + 1;                      // advance 2 mod 3
  }

  // ---- epilogue (LDS-staged, coalesced) ----
  const int rl = wr + ((lane >> 4) << 2);    // local row base of this lane's acc quads
  const int r0 = bm * 128 + rl;              // global row base (s512 lookup)
  ushort* epi = lds;
  __syncthreads();   // all main-loop LDS reads complete everywhere before overwrite

  if constexpr (EPI == 0) {
    // value(col c) = acc + Nyquist fold (first problem): n_st = c+1; c even -> -sv.
    // LDS tile [128][144] ushort (stride 144 = 72 words ≡ 8 mod 32 -> conflict-free).
#pragma unroll
    for (int m = 0; m < 4; ++m) {
      float4 sv4 = {0.f, 0.f, 0.f, 0.f};
      if (!second) sv4 = *(const float4*)(s512 + r0 + m * 16);
#pragma unroll
      for (int j = 0; j < 4; ++j) {
        float sv = ((const float*)&sv4)[j];
        int row = rl + m * 16 + j;
#pragma unroll
        for (int n = 0; n < 4; ++n) {
          int c = wc + n * 16 + lr;
          float par = second ? 0.0f : ((c & 1) ? sv : -sv);
          epi[row * 144 + c] = f2bf(acc[m][n][j] + par);
        }
      }
    }
    __syncthreads();
#pragma unroll
    for (int i = 0; i < 8; ++i) {
      int row = (tid >> 4) + i * 16;
      int co  = (tid & 15) << 3;
      bf16x8 v = *(const bf16x8*)(epi + row * 144 + co);
      *(bf16x8*)(C + (size_t)(bm * 128 + row) * ldc + bn * 128 + co) = v;
    }
  } else {
    // Activation: interleaved cols (2k=mag_k, 2k+1=phase_k); DPP pairs adjacent lanes.
    // Two LDS tiles [128][80] ushort (stride 80 = 40 words ≡ 8 mod 32 -> conflict-free).
    ushort* tA = epi;
    ushort* tB = epi + 128 * 80;
#pragma unroll
    for (int m = 0; m < 4; ++m) {
#pragma unroll
      for (int n = 0; n < 4; ++n) {
        const int cl  = wc + n * 16 + lr;            // local col 0..127
        const int kk  = (bn * 128 + cl) >> 1;        // global k index
        const bool isPhase = (cl & 1);
        const float bs = bias[isPhase ? 513 + kk : kk];
        ushort* dst = (isPhase ? tB : tA);
        const int kkl = cl >> 1;                     // local k 0..63
#pragma unroll
        for (int j = 0; j < 4; ++j) {
          float v = acc[m][n][j] + bs;
          float pv = dpp_xor1(v);
          float hm = isPhase ? pv : v;
          float hp = isPhase ? v : pv;
          float mag = fminf(fast_exp(hm), 100.0f);
          float outv = isPhase ? mag * fast_sin(hp) : mag * fast_cos(hp);
          dst[(rl + m * 16 + j) * 80 + kkl] = f2bf(outv);
        }
      }
    }
    __syncthreads();
#pragma unroll
    for (int i = 0; i < 4; ++i) {
      int row = (tid >> 3) + i * 32;
      int co  = (tid & 7) << 3;
      size_t go = (size_t)(bm * 128 + row) * ldc + bn * 64 + co;
      bf16x8 va = *(const bf16x8*)(tA + row * 80 + co);
      *(bf16x8*)(C + go) = va;
      bf16x8 vb = *(const bf16x8*)(tB + row * 80 + co);
      *(bf16x8*)(C2 + go) = vb;
    }
  }
}

// ---------------- overlap-add (4 samples/thread, aligned vector loads) ----------------
__global__ void k_oa(const ushort* __restrict__ E, const ushort* __restrict__ O,
                     float* __restrict__ out) {
  int u = blockIdx.x * 256 + threadIdx.x;       // 16 * 262144 groups of 4 samples
  int b  = u >> 18;
  int g  = u & 262143;
  int s  = (g << 2) + PADC;
  int t0 = s >> 8;
  int nb = s & 255;                             // multiple of 4
  float acc[4] = {0.f, 0.f, 0.f, 0.f};
  bool interior = (t0 >= 3) && (t0 < TFRM);
  float env[4];
#pragma unroll
  for (int j = 0; j < 4; ++j) env[j] = interior ? 1.5f : 0.0f;
#pragma unroll
  for (int q = 0; q < 4; ++q) {
    int t = t0 - q;
    if (t < 0 || t >= TFRM) continue;
    int n = nb + (q << 8);                      // multiple of 4, in [0, 1020]
    size_t base = ((size_t)(b << 12) + t) << 9; // row * 512
    float w[4];
#pragma unroll
    for (int j = 0; j < 4; ++j) {
      w[j] = 0.5f - 0.5f * __builtin_amdgcn_cosf((float)(n + j) * (1.0f / 1024.0f));
      if (!interior) env[j] += w[j] * w[j];
    }
    float d[4];
    if (n <= 508) {                             // direct: d[j] = E[n+j-1] - O[n+j-1]
      ushort4 e1 = *(const ushort4*)(E + base + n);
      ushort4 o1 = *(const ushort4*)(O + base + n);
      if (n >= 4) {
        ushort4 e0 = *(const ushort4*)(E + base + n - 4);
        ushort4 o0 = *(const ushort4*)(O + base + n - 4);
        d[0] = bf2f(e0.w) - bf2f(o0.w);
      } else d[0] = 0.0f;                       // n==0: w[0]=0 anyway
      d[1] = bf2f(e1.x) - bf2f(o1.x);
      d[2] = bf2f(e1.y) - bf2f(o1.y);
      d[3] = bf2f(e1.z) - bf2f(o1.z);
    } else if (n == 512) {                      // straddle: one aligned load at 508
      ushort4 e = *(const ushort4*)(E + base + 508);
      ushort4 o = *(const ushort4*)(O + base + 508);
      d[0] = bf2f(e.w) - bf2f(o.w);             // O_st[512]=0, sign moot
      d[1] = bf2f(e.z) + bf2f(o.z);
      d[2] = bf2f(e.y) + bf2f(o.y);
      d[3] = bf2f(e.x) + bf2f(o.x);
    } else {                                    // n >= 516 mirror: load at 1020-n
      ushort4 e = *(const ushort4*)(E + base + 1020 - n);
      ushort4 o = *(const ushort4*)(O + base + 1020 - n);
      d[0] = bf2f(e.w) + bf2f(o.w);
      d[1] = bf2f(e.z) + bf2f(o.z);
      d[2] = bf2f(e.y) + bf2f(o.y);
      d[3] = bf2f(e.x) + bf2f(o.x);
    }
#pragma unroll
    for (int j = 0; j < 4; ++j) acc[j] += w[j] * d[j];
  }
  float4 o4;
  o4.x = acc[0] / env[0]; o4.y = acc[1] / env[1];
  o4.z = acc[2] / env[2]; o4.w = acc[3] / env[3];
  *(float4*)(out + (size_t)u * 4) = o4;
}

// ---------------- launch ----------------
extern "C" void kernel_launch(void* const* d_in, const int* in_sizes, int n_in,
                              void* d_out, int out_size, void* d_ws, size_t ws_size,
                              hipStream_t stream) {
  const float* x    = (const float*)d_in[0];
  const float* W    = (const float*)d_in[1];
  const float* bias = (const float*)d_in[2];
  float* out = (float*)d_out;
  char* ws = (char*)d_ws;

  // ws layout (bytes):
  //   [0, 67108864)             xbf bf16 [65536][512] (dead after GEMM1)  ALIASED WITH E
  //   [67108864, 134217728)     h_a bf16 [65536][512]  (a_k = mag*cos)
  //   [134217728, 201326592)    h_b bf16 [65536][512]  (b_k = mag*sin)
  //   [201326592, 268435456)    O  bf16 [65536][512]
  //   [268435456, 269484032)    Wp bf16 [1024][512] (interleaved pairs, no Nyquist)
  //   [269484032, 270008320)    BasE bf16 [512][512]
  //   [270008320, 270532608)    BasO bf16 [512][512]
  //   [270532608, 270794752)    s512 fp32 [65536]
  ushort* xbf  = (ushort*)(ws + 0);
  ushort* Epp  = (ushort*)(ws + 0);
  ushort* h_a  = (ushort*)(ws + 67108864);
  ushort* h_b  = (ushort*)(ws + 134217728);
  ushort* Obuf = (ushort*)(ws + 201326592);
  ushort* Wp   = (ushort*)(ws + 268435456);
  ushort* basE = (ushort*)(ws + 269484032);
  ushort* basO = (ushort*)(ws + 270008320);
  float*  s512 = (float*) (ws + 270532608);

  k_prep_x<<<MROWS / 4, 256, 0, stream>>>(x, W, bias, xbf, s512);
  k_prep_w<<<(1024 * 512) / 256, 256, 0, stream>>>(W, Wp);
  k_basis<<<512, 256, 0, stream>>>(basE, basO);

  // GEMM1 + fused activation: h_a/h_b[65536][512] = act( xbf[65536][512] . Wp^T ), N=1024
  k_gemm<1><<<(MROWS / 128) * 8, 256, 0, stream>>>(
      xbf, nullptr, DIM, Wp, nullptr, DIM, h_a, h_b, 512, 8, 16, 0, bias, nullptr);

  // GEMM2 (fused pair): E = h_a . BasE^T (+Nyquist fold) ; O = h_b . BasO^T
  k_gemm<0><<<2 * (MROWS / 128) * 4, 256, 0, stream>>>(
      h_a, h_b, 512, basE, basO, 512, Epp, Obuf, 512, 4, 16, (MROWS / 128) * 4,
      nullptr, s512);

  // overlap-add, windowing, mirror reconstruction, envelope normalize, crop
  k_oa<<<(BATCH * OUTLEN) / 1024, 256, 0, stream>>>(Epp, Obuf, out);
}

// Round 13
// 397.497 us; speedup vs baseline: 1.0199x; 1.0199x over previous
//
#include <hip/hip_runtime.h>
#include <hip/hip_bf16.h>
#include <math.h>

// ---------------- constants ----------------
#define BATCH   16
#define TFRM    4096          // frames per batch (= L)
#define DIM     512
#define NFFT    1024
#define HOP     256
#define PADC    384           // (WIN-HOP)/2
#define MROWS   (BATCH*TFRM)  // 65536
#define OUTLEN  1048576       // per-batch output samples
#define TWO_PI_OVER_N 0.006135923151542565f  // 2*pi/1024
#define INV_TWO_PI    0.15915494309189535f   // 1/(2*pi)

typedef __bf16 bf16x8 __attribute__((ext_vector_type(8)));
typedef float  f32x4  __attribute__((ext_vector_type(4)));

__device__ __forceinline__ ushort f2bf(float f) {
  union { float f; unsigned u; } v; v.f = f;
  unsigned u = v.u;
  unsigned r = (u + 0x7FFFu + ((u >> 16) & 1u)) >> 16;
  return (ushort)r;
}
__device__ __forceinline__ float bf2f(ushort h) {
  union { unsigned u; float f; } v; v.u = ((unsigned)h) << 16;
  return v.f;
}
// HW transcendentals (single VALU op each; v_sin/v_cos take revolutions).
__device__ __forceinline__ float fast_sin(float x) { return __builtin_amdgcn_sinf(x * INV_TWO_PI); }
__device__ __forceinline__ float fast_cos(float x) { return __builtin_amdgcn_cosf(x * INV_TWO_PI); }
__device__ __forceinline__ float fast_exp(float x) { return __builtin_amdgcn_exp2f(x * 1.4426950408889634f); }
// lane-xor-1 exchange as a single VALU DPP op (quad_perm [1,0,3,2] = 0xB1).
__device__ __forceinline__ float dpp_xor1(float v) {
  return __int_as_float(__builtin_amdgcn_update_dpp(
      __float_as_int(v), __float_as_int(v), 0xB1, 0xF, 0xF, false));
}

// ---------------- prep: x fp32 -> bf16, fused Nyquist GEMV ----------------
__global__ void k_prep_x(const float* __restrict__ x, const float* __restrict__ W,
                         const float* __restrict__ bias,
                         ushort* __restrict__ xbf, float* __restrict__ s512) {
  const int row  = blockIdx.x * 4 + (threadIdx.x >> 6);
  const int lane = threadIdx.x & 63;
  const float* xr = x + (size_t)row * DIM + lane * 8;
  float4 v0 = *(const float4*)xr;
  float4 v1 = *(const float4*)(xr + 4);
  ushort4 u0, u1;
  u0.x = f2bf(v0.x); u0.y = f2bf(v0.y); u0.z = f2bf(v0.z); u0.w = f2bf(v0.w);
  u1.x = f2bf(v1.x); u1.y = f2bf(v1.y); u1.z = f2bf(v1.z); u1.w = f2bf(v1.w);
  ushort* xo = xbf + (size_t)row * DIM + lane * 8;
  *(ushort4*)xo = u0;
  *(ushort4*)(xo + 4) = u1;
  const float* w0 = W + 512 * DIM + lane * 8;    // mag row k=512
  const float* w1 = W + 1025 * DIM + lane * 8;   // phase row k=512
  float4 a0 = *(const float4*)w0, a1 = *(const float4*)(w0 + 4);
  float4 b0 = *(const float4*)w1, b1 = *(const float4*)(w1 + 4);
  float sm = v0.x*a0.x + v0.y*a0.y + v0.z*a0.z + v0.w*a0.w
           + v1.x*a1.x + v1.y*a1.y + v1.z*a1.z + v1.w*a1.w;
  float sp = v0.x*b0.x + v0.y*b0.y + v0.z*b0.z + v0.w*b0.w
           + v1.x*b1.x + v1.y*b1.y + v1.z*b1.z + v1.w*b1.w;
#pragma unroll
  for (int off = 32; off; off >>= 1) {
    sm += __shfl_down(sm, off);
    sp += __shfl_down(sp, off);
  }
  if (lane == 0) {
    float mag = fminf(fast_exp(sm + bias[512]), 100.0f);
    s512[row] = mag * fast_cos(sp + bias[1025]) * (1.0f / 1024.0f);
  }
}

// ---------------- prep: W fp32 -> bf16 interleaved [1024][512] ----------------
__global__ void k_prep_w(const float* __restrict__ W, ushort* __restrict__ o) {
  int i = blockIdx.x * 256 + threadIdx.x;          // over 1024*512
  int r = i >> 9;
  int c = i & 511;
  int orig = (r >> 1) + (r & 1) * 513;
  o[i] = f2bf(W[orig * DIM + c]);
}

// ---------------- basis: BasE/BasO [512 rows][512 K] bf16, row r -> n=r+1 ----------------
__global__ void k_basis(ushort* __restrict__ basE, ushort* __restrict__ basO) {
  int r = blockIdx.x;                              // 0..511
  int n = r + 1;
  for (int k = threadIdx.x; k < 512; k += 256) {
    float e, o;
    if (k == 0) { e = 1.0f / 1024.0f; o = 0.0f; }
    else {
      int ph = (k * n) & 1023;                     // exact integer phase reduction
      float ang = (float)ph * TWO_PI_OVER_N;
      e = 2.0f * cosf(ang) * (1.0f / 1024.0f);
      o = 2.0f * sinf(ang) * (1.0f / 1024.0f);
    }
    basE[r * 512 + k] = f2bf(e);
    basO[r * 512 + k] = f2bf(o);
  }
}

// ---------------- GEMM: C[m][n] = sum_k A[m][k]*Bt[n][k]  (bf16 in, fp32 acc)
// 128x128 tile, BK=32, 4 waves (2x2 of 64x64). B operands (basis/Wp — small,
// L2-resident, shared by all blocks) loaded DIRECTLY global->VGPR in MFMA fragment
// order. vs round 12: the B loads are INLINE ASM (untracked by the compiler's
// waitcnt insertion — round 12's C++ loads made the compiler emit conservative
// vmcnt waits before every consuming MFMA, serializing each tile behind freshly
// issued prefetches: 180 us). Correctness rests on the manual vmcnt(6) ladder
// (validated: round 12 passed) + sched_barrier(0) after each waitcnt (rule #18:
// hipcc hoists register-only MFMA past inline-asm waitcnts).
// LDS stages only A (ring-3 x 8 KB) -> per-tile LDS traffic 24 KB vs 48 KB, the
// measured per-CU bottleneck (3 resident blocks x 32 KB reads ≈ 1100 cyc/tile).
// vmcnt FIFO audit (6 ops/half-iter: 2 A-stage + 4 B-load): end-of-half vmcnt(6)
// lands tile u+1's A+B; tail vmcnt(0) then none. Granule-XOR swizzle on A keeps
// LDS conflict-free. XCD-chunked grid. nsplit>0: bid>=nsplit runs (A2,Bt2,C2).
// EPI=1: activation epilogue (LDS-staged, DPP mag/phase pairing), a_k->C, b_k->C2.
// EPI=0: E/O store unshifted; first problem folds (-1)^(i+1)*s512[row].
template<int EPI>
__global__ __launch_bounds__(256) void k_gemm(const ushort* A, const ushort* A2, int lda,
                                              const ushort* Bt, const ushort* Bt2, int ldb,
                                              ushort* C, ushort* C2, int ldc,
                                              int nbn, int NK, int nsplit,
                                              const float* __restrict__ bias,
                                              const float* __restrict__ s512) {
  __shared__ __align__(16) ushort lds[20480];  // 40 KB: ring-3 A slots (24K) / epilogue (40K)
  const int tid  = threadIdx.x;
  const int cpx  = gridDim.x >> 3;
  int bid  = (blockIdx.x & 7) * cpx + (blockIdx.x >> 3);   // XCD-chunked
  bool second = false;
  if (nsplit > 0 && bid >= nsplit) { second = true; A = A2; Bt = Bt2; C = C2; bid -= nsplit; }
  const int bm   = bid / nbn;
  const int bn   = bid - bm * nbn;
  const int lane = tid & 63;
  const int wv   = tid >> 6;
  const int wr   = (wv >> 1) * 64;
  const int wc   = (wv & 1) * 64;
  const int lr   = lane & 15;
  const int gx   = ((lane >> 4) ^ ((lane >> 1) & 3)) << 3; // swizzled A read granule

  f32x4 acc[4][4] = {};

  const int swz = ((tid & 3) ^ ((tid >> 3) & 3)) << 3;     // inverse-swizzled A source granule
  const ushort* gA = A + (size_t)(bm * 128 + (tid >> 2)) * lda + swz;
  auto stageA = [&](int t, int slot) {                     // 2 vmcnt ops
    const ushort* g0 = gA + t * 32;
    ushort* l = &lds[slot * 4096] + ((tid >> 6) << 9);
    __builtin_amdgcn_global_load_lds(
        (const __attribute__((address_space(1))) void*)g0,
        (__attribute__((address_space(3))) void*)l, 16, 0, 0);
    __builtin_amdgcn_global_load_lds(
        (const __attribute__((address_space(1))) void*)(g0 + (size_t)64 * lda),
        (__attribute__((address_space(3))) void*)(l + 2048), 16, 0, 0);
  };

  // B fragment base: row (bn*128 + wc + n*16 + lr), 8 bf16 at col t*32 + gq*8.
  const ushort* gB = Bt + (size_t)(bn * 128 + wc + lr) * ldb + ((lane >> 4) << 3);
  // Untracked vector loads: compiler sees the result as immediately ready and
  // inserts NO waits; the manual vmcnt ladder is the only ordering authority.
  auto loadB = [&](int t, bf16x8* bf) {                    // 4 vmcnt ops
#pragma unroll
    for (int n = 0; n < 4; ++n) {
      const ushort* p = gB + (size_t)(n * 16) * ldb + t * 32;
      asm volatile("global_load_dwordx4 %0, %1, off" : "=v"(bf[n]) : "v"(p));
    }
  };

  bf16x8 bE[4], bO[4];   // even-/odd-tile B fragment buffers (static names, rule #20)

  // prologue: FIFO [A0,B0 | A1,B1]; vmcnt(6) lands tile 0.
  stageA(0, 0); loadB(0, bE);
  asm volatile("" ::: "memory");
  stageA(1, 1); loadB(1, bO);
  asm volatile("s_waitcnt vmcnt(6)" ::: "memory");
  __builtin_amdgcn_sched_barrier(0);
  __syncthreads();

  int sl = 0;                                              // slot of even tile t
  for (int t = 0; t < NK; t += 2) {
    const int s0 = sl;
    const int s1 = (s0 >= 2) ? s0 - 2 : s0 + 1;            // (s0+1)%3
#pragma unroll
    for (int h = 0; h < 2; ++h) {
      const int u = t + h;
      const int su = h ? s1 : s0;
      const int sp = h ? s0 : ((s0 >= 1) ? s0 - 1 : 2);    // (su+2)%3
      const ushort* lA = &lds[su * 4096];
      bf16x8 aF[4];
#pragma unroll
      for (int m = 0; m < 4; ++m)
        aF[m] = *(const bf16x8*)(lA + (wr + m * 16 + lr) * 32 + gx);
      if (u + 2 < NK) stageA(u + 2, sp);
      if (h == 0) {
#pragma unroll
        for (int m = 0; m < 4; ++m)
#pragma unroll
          for (int n = 0; n < 4; ++n)
            acc[m][n] = __builtin_amdgcn_mfma_f32_16x16x32_bf16(aF[m], bE[n], acc[m][n], 0, 0, 0);
        if (u + 2 < NK) loadB(u + 2, bE);  // new SSA def: acts as double buffer
      } else {
#pragma unroll
        for (int m = 0; m < 4; ++m)
#pragma unroll
          for (int n = 0; n < 4; ++n)
            acc[m][n] = __builtin_amdgcn_mfma_f32_16x16x32_bf16(aF[m], bO[n], acc[m][n], 0, 0, 0);
        if (u + 2 < NK) loadB(u + 2, bO);
      }
      if (u + 2 < NK) {
        asm volatile("s_waitcnt vmcnt(6)" ::: "memory");
        __builtin_amdgcn_sched_barrier(0);
      } else if (u + 1 < NK) {
        asm volatile("s_waitcnt vmcnt(0)" ::: "memory");
        __builtin_amdgcn_sched_barrier(0);
      }
      if (u + 1 < NK) __syncthreads();
    }
    sl = (s1 >= 2) ? s1 - 2 : s1 + 1;                      // advance 2 mod 3
  }

  // ---- epilogue (LDS-staged, coalesced) ----
  const int rl = wr + ((lane >> 4) << 2);    // local row base of this lane's acc quads
  const int r0 = bm * 128 + rl;              // global row base (s512 lookup)
  ushort* epi = lds;
  __syncthreads();   // all main-loop LDS reads complete everywhere before overwrite

  if constexpr (EPI == 0) {
    // value(col c) = acc + Nyquist fold (first problem): n_st = c+1; c even -> -sv.
    // LDS tile [128][144] ushort (stride 144 = 72 words ≡ 8 mod 32 -> conflict-free).
#pragma unroll
    for (int m = 0; m < 4; ++m) {
      float4 sv4 = {0.f, 0.f, 0.f, 0.f};
      if (!second) sv4 = *(const float4*)(s512 + r0 + m * 16);
#pragma unroll
      for (int j = 0; j < 4; ++j) {
        float sv = ((const float*)&sv4)[j];
        int row = rl + m * 16 + j;
#pragma unroll
        for (int n = 0; n < 4; ++n) {
          int c = wc + n * 16 + lr;
          float par = second ? 0.0f : ((c & 1) ? sv : -sv);
          epi[row * 144 + c] = f2bf(acc[m][n][j] + par);
        }
      }
    }
    __syncthreads();
#pragma unroll
    for (int i = 0; i < 8; ++i) {
      int row = (tid >> 4) + i * 16;
      int co  = (tid & 15) << 3;
      bf16x8 v = *(const bf16x8*)(epi + row * 144 + co);
      *(bf16x8*)(C + (size_t)(bm * 128 + row) * ldc + bn * 128 + co) = v;
    }
  } else {
    // Activation: interleaved cols (2k=mag_k, 2k+1=phase_k); DPP pairs adjacent lanes.
    // Two LDS tiles [128][80] ushort (stride 80 = 40 words ≡ 8 mod 32 -> conflict-free).
    ushort* tA = epi;
    ushort* tB = epi + 128 * 80;
#pragma unroll
    for (int m = 0; m < 4; ++m) {
#pragma unroll
      for (int n = 0; n < 4; ++n) {
        const int cl  = wc + n * 16 + lr;            // local col 0..127
        const int kk  = (bn * 128 + cl) >> 1;        // global k index
        const bool isPhase = (cl & 1);
        const float bs = bias[isPhase ? 513 + kk : kk];
        ushort* dst = (isPhase ? tB : tA);
        const int kkl = cl >> 1;                     // local k 0..63
#pragma unroll
        for (int j = 0; j < 4; ++j) {
          float v = acc[m][n][j] + bs;
          float pv = dpp_xor1(v);
          float hm = isPhase ? pv : v;
          float hp = isPhase ? v : pv;
          float mag = fminf(fast_exp(hm), 100.0f);
          float outv = isPhase ? mag * fast_sin(hp) : mag * fast_cos(hp);
          dst[(rl + m * 16 + j) * 80 + kkl] = f2bf(outv);
        }
      }
    }
    __syncthreads();
#pragma unroll
    for (int i = 0; i < 4; ++i) {
      int row = (tid >> 3) + i * 32;
      int co  = (tid & 7) << 3;
      size_t go = (size_t)(bm * 128 + row) * ldc + bn * 64 + co;
      bf16x8 va = *(const bf16x8*)(tA + row * 80 + co);
      *(bf16x8*)(C + go) = va;
      bf16x8 vb = *(const bf16x8*)(tB + row * 80 + co);
      *(bf16x8*)(C2 + go) = vb;
    }
  }
}

// ---------------- overlap-add (4 samples/thread, aligned vector loads) ----------------
__global__ void k_oa(const ushort* __restrict__ E, const ushort* __restrict__ O,
                     float* __restrict__ out) {
  int u = blockIdx.x * 256 + threadIdx.x;       // 16 * 262144 groups of 4 samples
  int b  = u >> 18;
  int g  = u & 262143;
  int s  = (g << 2) + PADC;
  int t0 = s >> 8;
  int nb = s & 255;                             // multiple of 4
  float acc[4] = {0.f, 0.f, 0.f, 0.f};
  bool interior = (t0 >= 3) && (t0 < TFRM);
  float env[4];
#pragma unroll
  for (int j = 0; j < 4; ++j) env[j] = interior ? 1.5f : 0.0f;
#pragma unroll
  for (int q = 0; q < 4; ++q) {
    int t = t0 - q;
    if (t < 0 || t >= TFRM) continue;
    int n = nb + (q << 8);                      // multiple of 4, in [0, 1020]
    size_t base = ((size_t)(b << 12) + t) << 9; // row * 512
    float w[4];
#pragma unroll
    for (int j = 0; j < 4; ++j) {
      w[j] = 0.5f - 0.5f * __builtin_amdgcn_cosf((float)(n + j) * (1.0f / 1024.0f));
      if (!interior) env[j] += w[j] * w[j];
    }
    float d[4];
    if (n <= 508) {                             // direct: d[j] = E[n+j-1] - O[n+j-1]
      ushort4 e1 = *(const ushort4*)(E + base + n);
      ushort4 o1 = *(const ushort4*)(O + base + n);
      if (n >= 4) {
        ushort4 e0 = *(const ushort4*)(E + base + n - 4);
        ushort4 o0 = *(const ushort4*)(O + base + n - 4);
        d[0] = bf2f(e0.w) - bf2f(o0.w);
      } else d[0] = 0.0f;                       // n==0: w[0]=0 anyway
      d[1] = bf2f(e1.x) - bf2f(o1.x);
      d[2] = bf2f(e1.y) - bf2f(o1.y);
      d[3] = bf2f(e1.z) - bf2f(o1.z);
    } else if (n == 512) {                      // straddle: one aligned load at 508
      ushort4 e = *(const ushort4*)(E + base + 508);
      ushort4 o = *(const ushort4*)(O + base + 508);
      d[0] = bf2f(e.w) - bf2f(o.w);             // O_st[512]=0, sign moot
      d[1] = bf2f(e.z) + bf2f(o.z);
      d[2] = bf2f(e.y) + bf2f(o.y);
      d[3] = bf2f(e.x) + bf2f(o.x);
    } else {                                    // n >= 516 mirror: load at 1020-n
      ushort4 e = *(const ushort4*)(E + base + 1020 - n);
      ushort4 o = *(const ushort4*)(O + base + 1020 - n);
      d[0] = bf2f(e.w) + bf2f(o.w);
      d[1] = bf2f(e.z) + bf2f(o.z);
      d[2] = bf2f(e.y) + bf2f(o.y);
      d[3] = bf2f(e.x) + bf2f(o.x);
    }
#pragma unroll
    for (int j = 0; j < 4; ++j) acc[j] += w[j] * d[j];
  }
  float4 o4;
  o4.x = acc[0] / env[0]; o4.y = acc[1] / env[1];
  o4.z = acc[2] / env[2]; o4.w = acc[3] / env[3];
  *(float4*)(out + (size_t)u * 4) = o4;
}

// ---------------- launch ----------------
extern "C" void kernel_launch(void* const* d_in, const int* in_sizes, int n_in,
                              void* d_out, int out_size, void* d_ws, size_t ws_size,
                              hipStream_t stream) {
  const float* x    = (const float*)d_in[0];
  const float* W    = (const float*)d_in[1];
  const float* bias = (const float*)d_in[2];
  float* out = (float*)d_out;
  char* ws = (char*)d_ws;

  // ws layout (bytes):
  //   [0, 67108864)             xbf bf16 [65536][512] (dead after GEMM1)  ALIASED WITH E
  //   [67108864, 134217728)     h_a bf16 [65536][512]  (a_k = mag*cos)
  //   [134217728, 201326592)    h_b bf16 [65536][512]  (b_k = mag*sin)
  //   [201326592, 268435456)    O  bf16 [65536][512]
  //   [268435456, 269484032)    Wp bf16 [1024][512] (interleaved pairs, no Nyquist)
  //   [269484032, 270008320)    BasE bf16 [512][512]
  //   [270008320, 270532608)    BasO bf16 [512][512]
  //   [270532608, 270794752)    s512 fp32 [65536]
  ushort* xbf  = (ushort*)(ws + 0);
  ushort* Epp  = (ushort*)(ws + 0);
  ushort* h_a  = (ushort*)(ws + 67108864);
  ushort* h_b  = (ushort*)(ws + 134217728);
  ushort* Obuf = (ushort*)(ws + 201326592);
  ushort* Wp   = (ushort*)(ws + 268435456);
  ushort* basE = (ushort*)(ws + 269484032);
  ushort* basO = (ushort*)(ws + 270008320);
  float*  s512 = (float*) (ws + 270532608);

  k_prep_x<<<MROWS / 4, 256, 0, stream>>>(x, W, bias, xbf, s512);
  k_prep_w<<<(1024 * 512) / 256, 256, 0, stream>>>(W, Wp);
  k_basis<<<512, 256, 0, stream>>>(basE, basO);

  // GEMM1 + fused activation: h_a/h_b[65536][512] = act( xbf[65536][512] . Wp^T ), N=1024
  k_gemm<1><<<(MROWS / 128) * 8, 256, 0, stream>>>(
      xbf, nullptr, DIM, Wp, nullptr, DIM, h_a, h_b, 512, 8, 16, 0, bias, nullptr);

  // GEMM2 (fused pair): E = h_a . BasE^T (+Nyquist fold) ; O = h_b . BasO^T
  k_gemm<0><<<2 * (MROWS / 128) * 4, 256, 0, stream>>>(
      h_a, h_b, 512, basE, basO, 512, Epp, Obuf, 512, 4, 16, (MROWS / 128) * 4,
      nullptr, s512);

  // overlap-add, windowing, mirror reconstruction, envelope normalize, crop
  k_oa<<<(BATCH * OUTLEN) / 1024, 256, 0, stream>>>(Epp, Obuf, out);
}

// Round 14
// 299.511 us; speedup vs baseline: 1.3536x; 1.3272x over previous
//
#include <hip/hip_runtime.h>
#include <hip/hip_bf16.h>
#include <math.h>

// ---------------- constants ----------------
#define BATCH   16
#define TFRM    4096          // frames per batch (= L)
#define DIM     512
#define NFFT    1024
#define HOP     256
#define PADC    384           // (WIN-HOP)/2
#define MROWS   (BATCH*TFRM)  // 65536
#define OUTLEN  1048576       // per-batch output samples
#define TWO_PI_OVER_N 0.006135923151542565f  // 2*pi/1024
#define INV_TWO_PI    0.15915494309189535f   // 1/(2*pi)
#define EPS0    148           // EPI=0 epilogue LDS row stride (ushorts; 74 words, 74%8==2)
#define EPS1    68            // EPI=1 epilogue LDS row stride (ushorts; 34 words, 34%8==2)

typedef __bf16 bf16x8 __attribute__((ext_vector_type(8)));
typedef float  f32x4  __attribute__((ext_vector_type(4)));

__device__ __forceinline__ ushort f2bf(float f) {
  union { float f; unsigned u; } v; v.f = f;
  unsigned u = v.u;
  unsigned r = (u + 0x7FFFu + ((u >> 16) & 1u)) >> 16;
  return (ushort)r;
}
__device__ __forceinline__ float bf2f(ushort h) {
  union { unsigned u; float f; } v; v.u = ((unsigned)h) << 16;
  return v.f;
}
// HW transcendentals (single VALU op each; v_sin/v_cos take revolutions).
__device__ __forceinline__ float fast_sin(float x) { return __builtin_amdgcn_sinf(x * INV_TWO_PI); }
__device__ __forceinline__ float fast_cos(float x) { return __builtin_amdgcn_cosf(x * INV_TWO_PI); }
__device__ __forceinline__ float fast_exp(float x) { return __builtin_amdgcn_exp2f(x * 1.4426950408889634f); }
// lane-xor-1 exchange as a single VALU DPP op (quad_perm [1,0,3,2] = 0xB1).
__device__ __forceinline__ float dpp_xor1(float v) {
  return __int_as_float(__builtin_amdgcn_update_dpp(
      __float_as_int(v), __float_as_int(v), 0xB1, 0xF, 0xF, false));
}

// ---------------- prep: x fp32 -> bf16, fused Nyquist GEMV ----------------
__global__ void k_prep_x(const float* __restrict__ x, const float* __restrict__ W,
                         const float* __restrict__ bias,
                         ushort* __restrict__ xbf, float* __restrict__ s512) {
  const int row  = blockIdx.x * 4 + (threadIdx.x >> 6);
  const int lane = threadIdx.x & 63;
  const float* xr = x + (size_t)row * DIM + lane * 8;
  float4 v0 = *(const float4*)xr;
  float4 v1 = *(const float4*)(xr + 4);
  ushort4 u0, u1;
  u0.x = f2bf(v0.x); u0.y = f2bf(v0.y); u0.z = f2bf(v0.z); u0.w = f2bf(v0.w);
  u1.x = f2bf(v1.x); u1.y = f2bf(v1.y); u1.z = f2bf(v1.z); u1.w = f2bf(v1.w);
  ushort* xo = xbf + (size_t)row * DIM + lane * 8;
  *(ushort4*)xo = u0;
  *(ushort4*)(xo + 4) = u1;
  const float* w0 = W + 512 * DIM + lane * 8;    // mag row k=512
  const float* w1 = W + 1025 * DIM + lane * 8;   // phase row k=512
  float4 a0 = *(const float4*)w0, a1 = *(const float4*)(w0 + 4);
  float4 b0 = *(const float4*)w1, b1 = *(const float4*)(w1 + 4);
  float sm = v0.x*a0.x + v0.y*a0.y + v0.z*a0.z + v0.w*a0.w
           + v1.x*a1.x + v1.y*a1.y + v1.z*a1.z + v1.w*a1.w;
  float sp = v0.x*b0.x + v0.y*b0.y + v0.z*b0.z + v0.w*b0.w
           + v1.x*b1.x + v1.y*b1.y + v1.z*b1.z + v1.w*b1.w;
#pragma unroll
  for (int off = 32; off; off >>= 1) {
    sm += __shfl_down(sm, off);
    sp += __shfl_down(sp, off);
  }
  if (lane == 0) {
    float mag = fminf(fast_exp(sm + bias[512]), 100.0f);
    s512[row] = mag * fast_cos(sp + bias[1025]) * (1.0f / 1024.0f);
  }
}

// ---------------- prep: W -> bf16, FRAGMENT-MAJOR [1024 logical rows][512 K]
// Fragment (rg,t): 16 rows x 32 cols. ushort idx = (rg*16+t)*512 + lane*8 + j holds
// Blogical[rg*16+(lane&15)][t*32+((lane>>4)<<3)+j].  Logical row r: r=2k -> orig mag
// row k; r=2k+1 -> orig phase row 513+k (Nyquist rows excluded -> k_prep_x GEMV).
// A wave's MFMA B-fragment is then 64 lanes x 16B CONTIGUOUS (coalesced load).
__global__ void k_prep_w(const float* __restrict__ W, ushort* __restrict__ o) {
  int i = blockIdx.x * 256 + threadIdx.x;          // over 1024*512
  int j    = i & 7;
  int lane = (i >> 3) & 63;
  int fi   = i >> 9;                               // rg*16 + t
  int t    = fi & 15;
  int rg   = fi >> 4;
  int row  = rg * 16 + (lane & 15);                // logical interleaved row
  int col  = t * 32 + ((lane >> 4) << 3) + j;
  int orig = (row >> 1) + (row & 1) * 513;
  o[i] = f2bf(W[orig * DIM + col]);
}

// ---------------- basis: BasE/BasO FRAGMENT-MAJOR [512 logical rows][512 K]
// Logical row r -> output sample n = r+1.
// E[n][k] = (k==0 ? 1 : 2*cos(2pi*k*n/1024)) / 1024 ;  O[n][k] = 2*sin(...)/1024.
__global__ void k_basis(ushort* __restrict__ basE, ushort* __restrict__ basO) {
  int i = blockIdx.x * 256 + threadIdx.x;          // over 512*512
  int j    = i & 7;
  int lane = (i >> 3) & 63;
  int fi   = i >> 9;
  int t    = fi & 15;
  int rg   = fi >> 4;
  int r    = rg * 16 + (lane & 15);
  int k    = t * 32 + ((lane >> 4) << 3) + j;
  int n    = r + 1;
  float e, o;
  if (k == 0) { e = 1.0f / 1024.0f; o = 0.0f; }
  else {
    int ph = (k * n) & 1023;                       // exact integer phase reduction
    float ang = (float)ph * TWO_PI_OVER_N;
    e = 2.0f * cosf(ang) * (1.0f / 1024.0f);
    o = 2.0f * sinf(ang) * (1.0f / 1024.0f);
  }
  basE[i] = f2bf(e);
  basO[i] = f2bf(o);
}

// ---------------- GEMM: C[m][n] = sum_k A[m][k]*Blogical[n][k]  (bf16 in, fp32 acc)
// 128x128 tile, BK=32, 4 waves (2x2 of 64x64). A staged via LDS (ring-3 x 8 KB,
// global_load_lds w16, granule-XOR swizzle — conflict-free). B loaded DIRECTLY
// global->VGPR from the FRAGMENT-MAJOR layout: one fragment = 64 lanes x 16B
// contiguous -> fully coalesced (rounds 12/13's row-strided fragment loads had
// 16-way address divergence -> TA serialization was the 175us limiter, proven by
// the r13 null result with untracked asm). Loads stay inline-asm (untracked) with
// the validated manual vmcnt(6) ladder + sched_barrier(0) (rule #18).
// vmcnt FIFO (6 ops/half-iter: 2 A-stage + 4 B-load): end-of-half vmcnt(6) lands
// tile u+1's A+B; tail vmcnt(0) then none. XCD-chunked grid. nsplit>0: bid>=nsplit
// runs (A2,Bt2,C2). Epilogue LDS strides: row-step-4 writers need stride(words)%8==2
// -> EPS0=148, EPS1=68 ushorts (r11-13's 144/80 were a hidden 4-way conflict, 7.3e6).
// EPI=1: activation epilogue (DPP mag/phase pairing), a_k->C, b_k->C2.
// EPI=0: E/O store unshifted; first problem folds (-1)^(i+1)*s512[row].
template<int EPI>
__global__ __launch_bounds__(256) void k_gemm(const ushort* A, const ushort* A2, int lda,
                                              const ushort* Bt, const ushort* Bt2,
                                              ushort* C, ushort* C2, int ldc,
                                              int nbn, int NK, int nsplit,
                                              const float* __restrict__ bias,
                                              const float* __restrict__ s512) {
  __shared__ __align__(16) ushort lds[20480];  // 40 KB: ring-3 A slots (24K) / epilogue
  const int tid  = threadIdx.x;
  const int cpx  = gridDim.x >> 3;
  int bid  = (blockIdx.x & 7) * cpx + (blockIdx.x >> 3);   // XCD-chunked
  bool second = false;
  if (nsplit > 0 && bid >= nsplit) { second = true; A = A2; Bt = Bt2; C = C2; bid -= nsplit; }
  const int bm   = bid / nbn;
  const int bn   = bid - bm * nbn;
  const int lane = tid & 63;
  const int wv   = tid >> 6;
  const int wr   = (wv >> 1) * 64;
  const int wc   = (wv & 1) * 64;
  const int lr   = lane & 15;
  const int gx   = ((lane >> 4) ^ ((lane >> 1) & 3)) << 3; // swizzled A read granule

  f32x4 acc[4][4] = {};

  const int swz = ((tid & 3) ^ ((tid >> 3) & 3)) << 3;     // inverse-swizzled A source granule
  const ushort* gA = A + (size_t)(bm * 128 + (tid >> 2)) * lda + swz;
  auto stageA = [&](int t, int slot) {                     // 2 vmcnt ops
    const ushort* g0 = gA + t * 32;
    ushort* l = &lds[slot * 4096] + ((tid >> 6) << 9);
    __builtin_amdgcn_global_load_lds(
        (const __attribute__((address_space(1))) void*)g0,
        (__attribute__((address_space(3))) void*)l, 16, 0, 0);
    __builtin_amdgcn_global_load_lds(
        (const __attribute__((address_space(1))) void*)(g0 + (size_t)64 * lda),
        (__attribute__((address_space(3))) void*)(l + 2048), 16, 0, 0);
  };

  // B fragment-major: fragment (rg0+n, t) at ushort offset ((rg0+n)*16 + t)*512,
  // this lane's 8 values at +lane*8 — 64 lanes contiguous (one coalesced 1KB read).
  const int rg0 = bn * 8 + (wc >> 4);
  const ushort* gBf = Bt + ((size_t)rg0 * 16) * 512 + (size_t)lane * 8;
  auto loadB = [&](int t, bf16x8* bf) {                    // 4 vmcnt ops, untracked
#pragma unroll
    for (int n = 0; n < 4; ++n) {
      const ushort* p = gBf + (size_t)(n * 16 + t) * 512;
      asm volatile("global_load_dwordx4 %0, %1, off" : "=v"(bf[n]) : "v"(p));
    }
  };

  bf16x8 bE[4], bO[4];   // even-/odd-tile B fragment buffers (static names, rule #20)

  // prologue: FIFO [A0,B0 | A1,B1]; vmcnt(6) lands tile 0.
  stageA(0, 0); loadB(0, bE);
  asm volatile("" ::: "memory");
  stageA(1, 1); loadB(1, bO);
  asm volatile("s_waitcnt vmcnt(6)" ::: "memory");
  __builtin_amdgcn_sched_barrier(0);
  __syncthreads();

  int sl = 0;                                              // slot of even tile t
  for (int t = 0; t < NK; t += 2) {
    const int s0 = sl;
    const int s1 = (s0 >= 2) ? s0 - 2 : s0 + 1;            // (s0+1)%3
#pragma unroll
    for (int h = 0; h < 2; ++h) {
      const int u = t + h;
      const int su = h ? s1 : s0;
      const int sp = h ? s0 : ((s0 >= 1) ? s0 - 1 : 2);    // (su+2)%3
      const ushort* lA = &lds[su * 4096];
      bf16x8 aF[4];
#pragma unroll
      for (int m = 0; m < 4; ++m)
        aF[m] = *(const bf16x8*)(lA + (wr + m * 16 + lr) * 32 + gx);
      if (u + 2 < NK) stageA(u + 2, sp);
      if (h == 0) {
#pragma unroll
        for (int m = 0; m < 4; ++m)
#pragma unroll
          for (int n = 0; n < 4; ++n)
            acc[m][n] = __builtin_amdgcn_mfma_f32_16x16x32_bf16(aF[m], bE[n], acc[m][n], 0, 0, 0);
        if (u + 2 < NK) loadB(u + 2, bE);
      } else {
#pragma unroll
        for (int m = 0; m < 4; ++m)
#pragma unroll
          for (int n = 0; n < 4; ++n)
            acc[m][n] = __builtin_amdgcn_mfma_f32_16x16x32_bf16(aF[m], bO[n], acc[m][n], 0, 0, 0);
        if (u + 2 < NK) loadB(u + 2, bO);
      }
      if (u + 2 < NK) {
        asm volatile("s_waitcnt vmcnt(6)" ::: "memory");
        __builtin_amdgcn_sched_barrier(0);
      } else if (u + 1 < NK) {
        asm volatile("s_waitcnt vmcnt(0)" ::: "memory");
        __builtin_amdgcn_sched_barrier(0);
      }
      if (u + 1 < NK) __syncthreads();
    }
    sl = (s1 >= 2) ? s1 - 2 : s1 + 1;                      // advance 2 mod 3
  }

  // ---- epilogue (LDS-staged, coalesced) ----
  const int rl = wr + ((lane >> 4) << 2);    // local row base of this lane's acc quads
  const int r0 = bm * 128 + rl;              // global row base (s512 lookup)
  ushort* epi = lds;
  __syncthreads();   // all main-loop LDS reads complete everywhere before overwrite

  if constexpr (EPI == 0) {
    // value(col c) = acc + Nyquist fold (first problem): n_st = c+1; c even -> -sv.
#pragma unroll
    for (int m = 0; m < 4; ++m) {
      float4 sv4 = {0.f, 0.f, 0.f, 0.f};
      if (!second) sv4 = *(const float4*)(s512 + r0 + m * 16);
#pragma unroll
      for (int j = 0; j < 4; ++j) {
        float sv = ((const float*)&sv4)[j];
        int row = rl + m * 16 + j;
#pragma unroll
        for (int n = 0; n < 4; ++n) {
          int c = wc + n * 16 + lr;
          float par = second ? 0.0f : ((c & 1) ? sv : -sv);
          epi[row * EPS0 + c] = f2bf(acc[m][n][j] + par);
        }
      }
    }
    __syncthreads();
#pragma unroll
    for (int i = 0; i < 8; ++i) {
      int row = (tid >> 4) + i * 16;
      int co  = (tid & 15) << 3;
      bf16x8 v = *(const bf16x8*)(epi + row * EPS0 + co);
      *(bf16x8*)(C + (size_t)(bm * 128 + row) * ldc + bn * 128 + co) = v;
    }
  } else {
    // Activation: interleaved cols (2k=mag_k, 2k+1=phase_k); DPP pairs adjacent lanes.
    ushort* tA = epi;
    ushort* tB = epi + 128 * EPS1;
#pragma unroll
    for (int m = 0; m < 4; ++m) {
#pragma unroll
      for (int n = 0; n < 4; ++n) {
        const int cl  = wc + n * 16 + lr;            // local col 0..127
        const int kk  = (bn * 128 + cl) >> 1;        // global k index
        const bool isPhase = (cl & 1);
        const float bs = bias[isPhase ? 513 + kk : kk];
        ushort* dst = (isPhase ? tB : tA);
        const int kkl = cl >> 1;                     // local k 0..63
#pragma unroll
        for (int j = 0; j < 4; ++j) {
          float v = acc[m][n][j] + bs;
          float pv = dpp_xor1(v);
          float hm = isPhase ? pv : v;
          float hp = isPhase ? v : pv;
          float mag = fminf(fast_exp(hm), 100.0f);
          float outv = isPhase ? mag * fast_sin(hp) : mag * fast_cos(hp);
          dst[(rl + m * 16 + j) * EPS1 + kkl] = f2bf(outv);
        }
      }
    }
    __syncthreads();
#pragma unroll
    for (int i = 0; i < 4; ++i) {
      int row = (tid >> 3) + i * 32;
      int co  = (tid & 7) << 3;
      size_t go = (size_t)(bm * 128 + row) * ldc + bn * 64 + co;
      bf16x8 va = *(const bf16x8*)(tA + row * EPS1 + co);
      *(bf16x8*)(C + go) = va;
      bf16x8 vb = *(const bf16x8*)(tB + row * EPS1 + co);
      *(bf16x8*)(C2 + go) = vb;
    }
  }
}

// ---------------- overlap-add (4 samples/thread, aligned vector loads) ----------------
__global__ void k_oa(const ushort* __restrict__ E, const ushort* __restrict__ O,
                     float* __restrict__ out) {
  int u = blockIdx.x * 256 + threadIdx.x;       // 16 * 262144 groups of 4 samples
  int b  = u >> 18;
  int g  = u & 262143;
  int s  = (g << 2) + PADC;
  int t0 = s >> 8;
  int nb = s & 255;                             // multiple of 4
  float acc[4] = {0.f, 0.f, 0.f, 0.f};
  bool interior = (t0 >= 3) && (t0 < TFRM);
  float env[4];
#pragma unroll
  for (int j = 0; j < 4; ++j) env[j] = interior ? 1.5f : 0.0f;
#pragma unroll
  for (int q = 0; q < 4; ++q) {
    int t = t0 - q;
    if (t < 0 || t >= TFRM) continue;
    int n = nb + (q << 8);                      // multiple of 4, in [0, 1020]
    size_t base = ((size_t)(b << 12) + t) << 9; // row * 512
    float w[4];
#pragma unroll
    for (int j = 0; j < 4; ++j) {
      w[j] = 0.5f - 0.5f * __builtin_amdgcn_cosf((float)(n + j) * (1.0f / 1024.0f));
      if (!interior) env[j] += w[j] * w[j];
    }
    float d[4];
    if (n <= 508) {                             // direct: d[j] = E[n+j-1] - O[n+j-1]
      ushort4 e1 = *(const ushort4*)(E + base + n);
      ushort4 o1 = *(const ushort4*)(O + base + n);
      if (n >= 4) {
        ushort4 e0 = *(const ushort4*)(E + base + n - 4);
        ushort4 o0 = *(const ushort4*)(O + base + n - 4);
        d[0] = bf2f(e0.w) - bf2f(o0.w);
      } else d[0] = 0.0f;                       // n==0: w[0]=0 anyway
      d[1] = bf2f(e1.x) - bf2f(o1.x);
      d[2] = bf2f(e1.y) - bf2f(o1.y);
      d[3] = bf2f(e1.z) - bf2f(o1.z);
    } else if (n == 512) {                      // straddle: one aligned load at 508
      ushort4 e = *(const ushort4*)(E + base + 508);
      ushort4 o = *(const ushort4*)(O + base + 508);
      d[0] = bf2f(e.w) - bf2f(o.w);             // O_st[512]=0, sign moot
      d[1] = bf2f(e.z) + bf2f(o.z);
      d[2] = bf2f(e.y) + bf2f(o.y);
      d[3] = bf2f(e.x) + bf2f(o.x);
    } else {                                    // n >= 516 mirror: load at 1020-n
      ushort4 e = *(const ushort4*)(E + base + 1020 - n);
      ushort4 o = *(const ushort4*)(O + base + 1020 - n);
      d[0] = bf2f(e.w) + bf2f(o.w);
      d[1] = bf2f(e.z) + bf2f(o.z);
      d[2] = bf2f(e.y) + bf2f(o.y);
      d[3] = bf2f(e.x) + bf2f(o.x);
    }
#pragma unroll
    for (int j = 0; j < 4; ++j) acc[j] += w[j] * d[j];
  }
  float4 o4;
  o4.x = acc[0] / env[0]; o4.y = acc[1] / env[1];
  o4.z = acc[2] / env[2]; o4.w = acc[3] / env[3];
  *(float4*)(out + (size_t)u * 4) = o4;
}

// ---------------- launch ----------------
extern "C" void kernel_launch(void* const* d_in, const int* in_sizes, int n_in,
                              void* d_out, int out_size, void* d_ws, size_t ws_size,
                              hipStream_t stream) {
  const float* x    = (const float*)d_in[0];
  const float* W    = (const float*)d_in[1];
  const float* bias = (const float*)d_in[2];
  float* out = (float*)d_out;
  char* ws = (char*)d_ws;

  // ws layout (bytes):
  //   [0, 67108864)             xbf bf16 [65536][512] (dead after GEMM1)  ALIASED WITH E
  //   [67108864, 134217728)     h_a bf16 [65536][512]  (a_k = mag*cos)
  //   [134217728, 201326592)    h_b bf16 [65536][512]  (b_k = mag*sin)
  //   [201326592, 268435456)    O  bf16 [65536][512]
  //   [268435456, 269484032)    Wp bf16 fragment-major [1024 x 512]
  //   [269484032, 270008320)    BasE bf16 fragment-major [512 x 512]
  //   [270008320, 270532608)    BasO bf16 fragment-major [512 x 512]
  //   [270532608, 270794752)    s512 fp32 [65536]
  ushort* xbf  = (ushort*)(ws + 0);
  ushort* Epp  = (ushort*)(ws + 0);
  ushort* h_a  = (ushort*)(ws + 67108864);
  ushort* h_b  = (ushort*)(ws + 134217728);
  ushort* Obuf = (ushort*)(ws + 201326592);
  ushort* Wp   = (ushort*)(ws + 268435456);
  ushort* basE = (ushort*)(ws + 269484032);
  ushort* basO = (ushort*)(ws + 270008320);
  float*  s512 = (float*) (ws + 270532608);

  k_prep_x<<<MROWS / 4, 256, 0, stream>>>(x, W, bias, xbf, s512);
  k_prep_w<<<(1024 * 512) / 256, 256, 0, stream>>>(W, Wp);
  k_basis<<<(512 * 512) / 256, 256, 0, stream>>>(basE, basO);

  // GEMM1 + fused activation: h_a/h_b[65536][512] = act( xbf[65536][512] . Wp^T ), N=1024
  k_gemm<1><<<(MROWS / 128) * 8, 256, 0, stream>>>(
      xbf, nullptr, DIM, Wp, nullptr, h_a, h_b, 512, 8, 16, 0, bias, nullptr);

  // GEMM2 (fused pair): E = h_a . BasE^T (+Nyquist fold) ; O = h_b . BasO^T
  k_gemm<0><<<2 * (MROWS / 128) * 4, 256, 0, stream>>>(
      h_a, h_b, 512, basE, basO, Epp, Obuf, 512, 4, 16, (MROWS / 128) * 4,
      nullptr, s512);

  // overlap-add, windowing, mirror reconstruction, envelope normalize, crop
  k_oa<<<(BATCH * OUTLEN) / 1024, 256, 0, stream>>>(Epp, Obuf, out);
}